// Round 1
// baseline (910.306 us; speedup 1.0000x reference)
//
#include <hip/hip_runtime.h>
#include <cstdint>

#define BEPS 1e-5f

// ---------------- 1x1 conv as batched GEMM ----------------
// out[b][co][p] = bias[co] + sum_ci w[co][ci] * in[b][ci][p]
// tiles: BM=BN=128, BK=32, 256 threads, 8x8 micro-tile
__global__ __launch_bounds__(256) void gemm1x1(
    const float* __restrict__ in, const float* __restrict__ w,
    const float* __restrict__ bias, float* __restrict__ out,
    int Ci, int Co, int P)
{
    const int b  = blockIdx.z;
    const int p0 = blockIdx.x * 128;
    const int c0 = blockIdx.y * 128;
    const int tid = threadIdx.x;
    const int tx = tid & 15;   // p
    const int ty = tid >> 4;   // co

    __shared__ float sW[32][132];  // [k][co]
    __shared__ float sX[32][132];  // [k][p]

    const float* inb = in + (size_t)b * Ci * P;

    float acc[8][8];
#pragma unroll
    for (int i = 0; i < 8; ++i) {
#pragma unroll
        for (int j = 0; j < 8; ++j) acc[i][j] = 0.f;
    }

    for (int k0 = 0; k0 < Ci; k0 += 32) {
        // W tile [c0..+127][k0..+31] -> sW[k][co]
#pragma unroll
        for (int i = 0; i < 4; ++i) {
            int f  = tid + i * 256;        // 0..1023 float4 index
            int co = f >> 3;
            int k4 = (f & 7) << 2;
            float4 v = *(const float4*)&w[(size_t)(c0 + co) * Ci + k0 + k4];
            sW[k4 + 0][co] = v.x;
            sW[k4 + 1][co] = v.y;
            sW[k4 + 2][co] = v.z;
            sW[k4 + 3][co] = v.w;
        }
        // X tile [k0..+31][p0..+127] -> sX[k][p]
#pragma unroll
        for (int i = 0; i < 4; ++i) {
            int f  = tid + i * 256;
            int k  = f >> 5;
            int p4 = (f & 31) << 2;
            float4 v;
            if (p0 + p4 < P) v = *(const float4*)&inb[(size_t)(k0 + k) * P + p0 + p4];
            else             v = make_float4(0.f, 0.f, 0.f, 0.f);
            *(float4*)&sX[k][p4] = v;
        }
        __syncthreads();

#pragma unroll 8
        for (int kk = 0; kk < 32; ++kk) {
            float a[8], xv[8];
            *(float4*)&a[0]  = *(const float4*)&sW[kk][ty * 8];
            *(float4*)&a[4]  = *(const float4*)&sW[kk][ty * 8 + 4];
            *(float4*)&xv[0] = *(const float4*)&sX[kk][tx * 8];
            *(float4*)&xv[4] = *(const float4*)&sX[kk][tx * 8 + 4];
#pragma unroll
            for (int i = 0; i < 8; ++i) {
#pragma unroll
                for (int j = 0; j < 8; ++j) acc[i][j] = fmaf(a[i], xv[j], acc[i][j]);
            }
        }
        __syncthreads();
    }

    float* outb = out + (size_t)b * Co * P;
#pragma unroll
    for (int i = 0; i < 8; ++i) {
        int co = c0 + ty * 8 + i;
        float bi = bias[co];
        size_t rb = (size_t)co * P;
#pragma unroll
        for (int j = 0; j < 8; ++j) {
            int p = p0 + tx * 8 + j;
            if (p < P) outb[rb + p] = acc[i][j] + bi;
        }
    }
}

// ---------------- depthwise 5x5 stride-2 + BN ----------------
__global__ __launch_bounds__(256) void dwconv_bn(
    const float* __restrict__ in, const float* __restrict__ w5,
    const float* __restrict__ cb, const float* __restrict__ g,
    const float* __restrict__ bb, const float* __restrict__ m,
    const float* __restrict__ v, float* __restrict__ out,
    int Hin, int Win, int Hout, int Wout, int stride, int total)
{
    int idx = blockIdx.x * 256 + threadIdx.x;
    if (idx >= total) return;
    int x = idx % Wout;
    int t = idx / Wout;
    int y = t % Hout;
    t /= Hout;
    int c = t & 255;
    int b = t >> 8;
    const float* ib = in + (size_t)(b * 256 + c) * Hin * Win;
    const float* wc = w5 + c * 25;
    float s = 0.f;
#pragma unroll
    for (int dy = 0; dy < 5; ++dy) {
        int iy = y * stride + dy - 2;
        if (iy < 0 || iy >= Hin) continue;
#pragma unroll
        for (int dx = 0; dx < 5; ++dx) {
            int ix = x * stride + dx - 2;
            if (ix < 0 || ix >= Win) continue;
            s = fmaf(wc[dy * 5 + dx], ib[iy * Win + ix], s);
        }
    }
    s += cb[c];
    float sc = g[c] * rsqrtf(v[c] + BEPS);
    out[idx] = (s - m[c]) * sc + bb[c];
}

// ---------------- attention: per (b,h), Q=3136x32, K/V=196x32 ----------------
__global__ __launch_bounds__(512) void attn_kernel(
    const float* __restrict__ qloc,   // [B][256][3136]
    const float* __restrict__ kvbuf,  // [B][512][196]
    float* __restrict__ gf)           // [B][256][3136]
{
    const int b = blockIdx.z;
    const int h = blockIdx.y;
    const int p = blockIdx.x * 512 + threadIdx.x;

    __shared__ float sK[196][36];
    __shared__ float sV[196][36];

    const float* kp = kvbuf + ((size_t)b * 512 + h * 32) * 196;
    const float* vp = kvbuf + ((size_t)b * 512 + 256 + h * 32) * 196;
    for (int idx = threadIdx.x; idx < 196 * 32; idx += 512) {
        int d = idx / 196;
        int j = idx - d * 196;
        sK[j][d] = kp[idx];
        sV[j][d] = vp[idx];
    }
    __syncthreads();

    if (p >= 3136) return;

    const float scal = 0.17677669529663687f;  // 32^-0.5
    const float* qp = qloc + ((size_t)b * 256 + h * 32) * 3136 + p;
    float q[32];
#pragma unroll
    for (int d = 0; d < 32; ++d) q[d] = qp[(size_t)d * 3136] * scal;

    float acc[32];
#pragma unroll
    for (int d = 0; d < 32; ++d) acc[d] = 0.f;
    float ssum = 0.f;

    // scores are ~O(0.2): softmax without max-subtraction is exact-safe
    for (int j = 0; j < 196; ++j) {
        float s = 0.f;
#pragma unroll
        for (int d = 0; d < 32; ++d) s = fmaf(q[d], sK[j][d], s);
        float e = __expf(s);
        ssum += e;
#pragma unroll
        for (int d = 0; d < 32; ++d) acc[d] = fmaf(e, sV[j][d], acc[d]);
    }
    float inv = 1.f / ssum;
    float* op = gf + ((size_t)b * 256 + h * 32) * 3136 + p;
#pragma unroll
    for (int d = 0; d < 32; ++d) op[(size_t)d * 3136] = acc[d] * inv;
}

// ---------------- local dwconv 5x5 s1 + silu + global gating ----------------
__global__ __launch_bounds__(256) void gate_kernel(
    const float* __restrict__ ql, const float* __restrict__ w5,
    const float* __restrict__ cb, const float* __restrict__ gfb,
    float* __restrict__ t_out, int total)
{
    int idx = blockIdx.x * 256 + threadIdx.x;
    if (idx >= total) return;
    int x = idx % 56;
    int t = idx / 56;
    int y = t % 56;
    t /= 56;
    int c = t & 255;
    int b = t >> 8;
    const float* ib = ql + (size_t)(b * 256 + c) * 3136;
    const float* wc = w5 + c * 25;
    float s = 0.f;
#pragma unroll
    for (int dy = 0; dy < 5; ++dy) {
        int iy = y + dy - 2;
        if (iy < 0 || iy >= 56) continue;
#pragma unroll
        for (int dx = 0; dx < 5; ++dx) {
            int ix = x + dx - 2;
            if (ix < 0 || ix >= 56) continue;
            s = fmaf(wc[dy * 5 + dx], ib[iy * 56 + ix], s);
        }
    }
    s += cb[c];
    float gv = gfb[idx];
    float sl = s / (1.f + __expf(-s));        // silu(lf)
    float sg = 1.f / (1.f + __expf(-gv));     // sigmoid(gf)
    t_out[idx] = sl * sg * gv;
}

extern "C" void kernel_launch(void* const* d_in, const int* in_sizes, int n_in,
                              void* d_out, int out_size, void* d_ws, size_t ws_size,
                              hipStream_t stream)
{
    const float* x     = (const float*)d_in[0];
    const float* q_w   = (const float*)d_in[1];
    const float* q_b   = (const float*)d_in[2];
    const float* kv_w  = (const float*)d_in[3];
    const float* kv_b  = (const float*)d_in[4];
    const float* p0_w  = (const float*)d_in[5];
    const float* p0_b  = (const float*)d_in[6];
    const float* bn0_g = (const float*)d_in[7];
    const float* bn0_b = (const float*)d_in[8];
    const float* bn0_m = (const float*)d_in[9];
    const float* bn0_v = (const float*)d_in[10];
    const float* pl0_w = (const float*)d_in[11];
    const float* pl0_b = (const float*)d_in[12];
    const float* p1_w  = (const float*)d_in[13];
    const float* p1_b  = (const float*)d_in[14];
    const float* bn1_g = (const float*)d_in[15];
    const float* bn1_b = (const float*)d_in[16];
    const float* bn1_m = (const float*)d_in[17];
    const float* bn1_v = (const float*)d_in[18];
    const float* loc_w = (const float*)d_in[19];
    const float* loc_b = (const float*)d_in[20];
    const float* mix_w = (const float*)d_in[21];
    const float* mix_b = (const float*)d_in[22];

    float* qlocal = (float*)d_out;           // q_local lives in d_out; overwritten by final mix
    float* ws  = (float*)d_ws;
    float* gf  = ws;                          // 12845056 floats
    float* tb  = ws + 12845056;               // 12845056 floats (p-chain sublets this region)
    float* p0  = tb;                          // 3211264
    float* pl0 = tb + 3211264;                // 3211264
    float* p1  = tb + 6422528;                // 802816
    float* kv  = tb + 7225344;                // 1605632

    // 1. q projection (1x1)
    gemm1x1<<<dim3(25, 2, 16), 256, 0, stream>>>(x, q_w, q_b, qlocal, 256, 256, 3136);
    // 2. dwconv s2 + BN0
    dwconv_bn<<<dim3(12544), 256, 0, stream>>>(x, p0_w, p0_b, bn0_g, bn0_b, bn0_m, bn0_v,
                                               p0, 56, 56, 28, 28, 2, 3211264);
    // 3. pl0 (1x1)
    gemm1x1<<<dim3(7, 2, 16), 256, 0, stream>>>(p0, pl0_w, pl0_b, pl0, 256, 256, 784);
    // 4. dwconv s2 + BN1
    dwconv_bn<<<dim3(3136), 256, 0, stream>>>(pl0, p1_w, p1_b, bn1_g, bn1_b, bn1_m, bn1_v,
                                              p1, 28, 28, 14, 14, 2, 802816);
    // 5. kv projection (1x1, Co=512)
    gemm1x1<<<dim3(2, 4, 16), 256, 0, stream>>>(p1, kv_w, kv_b, kv, 256, 512, 196);
    // 6. attention -> global_feat
    attn_kernel<<<dim3(7, 8, 16), 512, 0, stream>>>(qlocal, kv, gf);
    // 7. local dwconv + silu + gating -> t
    gate_kernel<<<dim3(50176), 256, 0, stream>>>(qlocal, loc_w, loc_b, gf, tb, 12845056);
    // 8. mix (1x1) -> d_out
    gemm1x1<<<dim3(25, 2, 16), 256, 0, stream>>>(tb, mix_w, mix_b, qlocal, 256, 256, 3136);
}

// Round 3
// 707.918 us; speedup vs baseline: 1.2859x; 1.2859x over previous
//
#include <hip/hip_runtime.h>
#include <cstdint>

#define BEPS 1e-5f

typedef __attribute__((ext_vector_type(8))) short short8;
typedef __attribute__((ext_vector_type(4))) float f32x4;

static __device__ __forceinline__ uint32_t f2bf(float f) {
    union { float f; uint32_t u; } v; v.f = f;
    return (v.u + 0x7FFFu + ((v.u >> 16) & 1u)) >> 16;   // RNE
}
static __device__ __forceinline__ uint32_t pk2(float lo, float hi) {
    return (f2bf(hi) << 16) | (f2bf(lo) & 0xFFFFu);
}

// ---------------- 1x1 conv as batched GEMM, bf16 MFMA ----------------
// out[b][co][p] = bias[co] + sum_ci w[co][ci] * in[b][ci][p]
// BM=BN=128, BK=32, 256 threads = 4 waves (2x2), 64x64 per wave, 16x16x32 MFMA
__global__ __launch_bounds__(256) void gemm1x1_mfma(
    const float* __restrict__ in, const float* __restrict__ w,
    const float* __restrict__ bias, float* __restrict__ out,
    int Ci, int Co, int P)
{
    const int b  = blockIdx.z;
    const int p0 = blockIdx.x * 128;
    const int c0 = blockIdx.y * 128;
    const int tid  = threadIdx.x;
    const int lane = tid & 63;
    const int wave = tid >> 6;
    const int wm = wave >> 1, wn = wave & 1;
    const int l15 = lane & 15;
    const int kg  = lane >> 4;     // 0..3

    // pad rows to 40 shorts (80 B): frag reads start at 8 distinct bank-quads
    __shared__ short sA[128][40];  // [co][k]
    __shared__ short sB[128][40];  // [p][k]  (X transposed)

    f32x4 acc[4][4] = {};

    const float* inb = in + (size_t)b * Ci * P;

    // staging indices (loop-invariant)
    const int arow  = tid >> 1;           // 0..127
    const int ahalf = (tid & 1) * 16;     // 0 / 16
    const int bp    = tid & 127;          // 0..127
    const int bhalf = (tid >> 7) * 16;    // 0 / 16
    const bool bok  = (p0 + bp) < P;

    for (int k0 = 0; k0 < Ci; k0 += 32) {
        // ---- stage A: W[c0+arow][k0+ahalf .. +15] -> sA[arow][ahalf..]
        {
            const float* src = &w[(size_t)(c0 + arow) * Ci + k0 + ahalf];
            float4 f0 = *(const float4*)(src + 0);
            float4 f1 = *(const float4*)(src + 4);
            float4 f2 = *(const float4*)(src + 8);
            float4 f3 = *(const float4*)(src + 12);
            uint4 q0, q1;
            q0.x = pk2(f0.x, f0.y); q0.y = pk2(f0.z, f0.w);
            q0.z = pk2(f1.x, f1.y); q0.w = pk2(f1.z, f1.w);
            q1.x = pk2(f2.x, f2.y); q1.y = pk2(f2.z, f2.w);
            q1.z = pk2(f3.x, f3.y); q1.w = pk2(f3.z, f3.w);
            *(uint4*)&sA[arow][ahalf]     = q0;
            *(uint4*)&sA[arow][ahalf + 8] = q1;
        }
        // ---- stage B: X[k0+bhalf+i][p0+bp] -> sB[bp][bhalf+i]
        {
            const float* src = &inb[(size_t)(k0 + bhalf) * P + p0 + bp];
            float fv[16];
#pragma unroll
            for (int i = 0; i < 16; ++i)
                fv[i] = bok ? src[(size_t)i * P] : 0.f;
            uint4 q0, q1;
            q0.x = pk2(fv[0], fv[1]);  q0.y = pk2(fv[2], fv[3]);
            q0.z = pk2(fv[4], fv[5]);  q0.w = pk2(fv[6], fv[7]);
            q1.x = pk2(fv[8], fv[9]);  q1.y = pk2(fv[10], fv[11]);
            q1.z = pk2(fv[12], fv[13]); q1.w = pk2(fv[14], fv[15]);
            *(uint4*)&sB[bp][bhalf]     = q0;
            *(uint4*)&sB[bp][bhalf + 8] = q1;
        }
        __syncthreads();

        short8 aF[4], bF[4];
#pragma unroll
        for (int m = 0; m < 4; ++m)
            aF[m] = *(const short8*)&sA[wm * 64 + m * 16 + l15][kg * 8];
#pragma unroll
        for (int n = 0; n < 4; ++n)
            bF[n] = *(const short8*)&sB[wn * 64 + n * 16 + l15][kg * 8];
#pragma unroll
        for (int m = 0; m < 4; ++m)
#pragma unroll
            for (int n = 0; n < 4; ++n)
                acc[m][n] = __builtin_amdgcn_mfma_f32_16x16x32_bf16(aF[m], bF[n], acc[m][n], 0, 0, 0);
        __syncthreads();
    }

    // ---- epilogue: C/D layout col=lane&15, row=(lane>>4)*4+j (m89)
    float* outb = out + (size_t)b * Co * P;
#pragma unroll
    for (int m = 0; m < 4; ++m) {
        int row = c0 + wm * 64 + m * 16 + kg * 4;
#pragma unroll
        for (int n = 0; n < 4; ++n) {
            int col = p0 + wn * 64 + n * 16 + l15;
            if (col < P) {
#pragma unroll
                for (int j = 0; j < 4; ++j)
                    outb[(size_t)(row + j) * P + col] = acc[m][n][j] + bias[row + j];
            }
        }
    }
}

// ---------------- depthwise 5x5 stride-2 + BN ----------------
__global__ __launch_bounds__(256) void dwconv_bn(
    const float* __restrict__ in, const float* __restrict__ w5,
    const float* __restrict__ cb, const float* __restrict__ g,
    const float* __restrict__ bb, const float* __restrict__ m,
    const float* __restrict__ v, float* __restrict__ out,
    int Hin, int Win, int Hout, int Wout, int stride, int total)
{
    int idx = blockIdx.x * 256 + threadIdx.x;
    if (idx >= total) return;
    int x = idx % Wout;
    int t = idx / Wout;
    int y = t % Hout;
    t /= Hout;
    int c = t & 255;
    int b = t >> 8;
    const float* ib = in + (size_t)(b * 256 + c) * Hin * Win;
    const float* wc = w5 + c * 25;
    float s = 0.f;
#pragma unroll
    for (int dy = 0; dy < 5; ++dy) {
        int iy = y * stride + dy - 2;
        if (iy < 0 || iy >= Hin) continue;
#pragma unroll
        for (int dx = 0; dx < 5; ++dx) {
            int ix = x * stride + dx - 2;
            if (ix < 0 || ix >= Win) continue;
            s = fmaf(wc[dy * 5 + dx], ib[iy * Win + ix], s);
        }
    }
    s += cb[c];
    float sc = g[c] * rsqrtf(v[c] + BEPS);
    out[idx] = (s - m[c]) * sc + bb[c];
}

// ---------------- attention: per (b,h), Q=3136x32, K/V=196x32 ----------------
__global__ __launch_bounds__(512) void attn_kernel(
    const float* __restrict__ qloc,   // [B][256][3136]
    const float* __restrict__ kvbuf,  // [B][512][196]
    float* __restrict__ gf)           // [B][256][3136]
{
    const int b = blockIdx.z;
    const int h = blockIdx.y;
    const int p = blockIdx.x * 512 + threadIdx.x;

    __shared__ float sK[196][36];
    __shared__ float sV[196][36];

    const float* kp = kvbuf + ((size_t)b * 512 + h * 32) * 196;
    const float* vp = kvbuf + ((size_t)b * 512 + 256 + h * 32) * 196;
    for (int idx = threadIdx.x; idx < 196 * 32; idx += 512) {
        int d = idx / 196;
        int j = idx - d * 196;
        sK[j][d] = kp[idx];
        sV[j][d] = vp[idx];
    }
    __syncthreads();

    if (p >= 3136) return;

    const float scal = 0.17677669529663687f;  // 32^-0.5
    const float* qp = qloc + ((size_t)b * 256 + h * 32) * 3136 + p;
    float q[32];
#pragma unroll
    for (int d = 0; d < 32; ++d) q[d] = qp[(size_t)d * 3136] * scal;

    float acc[32];
#pragma unroll
    for (int d = 0; d < 32; ++d) acc[d] = 0.f;
    float ssum = 0.f;

    for (int j = 0; j < 196; ++j) {
        float s = 0.f;
#pragma unroll
        for (int d = 0; d < 32; ++d) s = fmaf(q[d], sK[j][d], s);
        float e = __expf(s);
        ssum += e;
#pragma unroll
        for (int d = 0; d < 32; ++d) acc[d] = fmaf(e, sV[j][d], acc[d]);
    }
    float inv = 1.f / ssum;
    float* op = gf + ((size_t)b * 256 + h * 32) * 3136 + p;
#pragma unroll
    for (int d = 0; d < 32; ++d) op[(size_t)d * 3136] = acc[d] * inv;
}

// ---------------- local dwconv 5x5 s1 + silu + global gating ----------------
__global__ __launch_bounds__(256) void gate_kernel(
    const float* __restrict__ ql, const float* __restrict__ w5,
    const float* __restrict__ cb, const float* __restrict__ gfb,
    float* __restrict__ t_out, int total)
{
    int idx = blockIdx.x * 256 + threadIdx.x;
    if (idx >= total) return;
    int x = idx % 56;
    int t = idx / 56;
    int y = t % 56;
    t /= 56;
    int c = t & 255;
    int b = t >> 8;
    const float* ib = ql + (size_t)(b * 256 + c) * 3136;
    const float* wc = w5 + c * 25;
    float s = 0.f;
#pragma unroll
    for (int dy = 0; dy < 5; ++dy) {
        int iy = y + dy - 2;
        if (iy < 0 || iy >= 56) continue;
#pragma unroll
        for (int dx = 0; dx < 5; ++dx) {
            int ix = x + dx - 2;
            if (ix < 0 || ix >= 56) continue;
            s = fmaf(wc[dy * 5 + dx], ib[iy * 56 + ix], s);
        }
    }
    s += cb[c];
    float gv = gfb[idx];
    float sl = s / (1.f + __expf(-s));        // silu(lf)
    float sg = 1.f / (1.f + __expf(-gv));     // sigmoid(gf)
    t_out[idx] = sl * sg * gv;
}

extern "C" void kernel_launch(void* const* d_in, const int* in_sizes, int n_in,
                              void* d_out, int out_size, void* d_ws, size_t ws_size,
                              hipStream_t stream)
{
    const float* x     = (const float*)d_in[0];
    const float* q_w   = (const float*)d_in[1];
    const float* q_b   = (const float*)d_in[2];
    const float* kv_w  = (const float*)d_in[3];
    const float* kv_b  = (const float*)d_in[4];
    const float* p0_w  = (const float*)d_in[5];
    const float* p0_b  = (const float*)d_in[6];
    const float* bn0_g = (const float*)d_in[7];
    const float* bn0_b = (const float*)d_in[8];
    const float* bn0_m = (const float*)d_in[9];
    const float* bn0_v = (const float*)d_in[10];
    const float* pl0_w = (const float*)d_in[11];
    const float* pl0_b = (const float*)d_in[12];
    const float* p1_w  = (const float*)d_in[13];
    const float* p1_b  = (const float*)d_in[14];
    const float* bn1_g = (const float*)d_in[15];
    const float* bn1_b = (const float*)d_in[16];
    const float* bn1_m = (const float*)d_in[17];
    const float* bn1_v = (const float*)d_in[18];
    const float* loc_w = (const float*)d_in[19];
    const float* loc_b = (const float*)d_in[20];
    const float* mix_w = (const float*)d_in[21];
    const float* mix_b = (const float*)d_in[22];

    float* qlocal = (float*)d_out;           // q_local lives in d_out; overwritten by final mix
    float* ws  = (float*)d_ws;
    float* gf  = ws;                          // 12845056 floats
    float* tb  = ws + 12845056;               // 12845056 floats (p-chain sublets this region)
    float* p0  = tb;                          // 3211264
    float* pl0 = tb + 3211264;                // 3211264
    float* p1  = tb + 6422528;                // 802816
    float* kv  = tb + 7225344;                // 1605632

    // 1. q projection (1x1)
    gemm1x1_mfma<<<dim3(25, 2, 16), 256, 0, stream>>>(x, q_w, q_b, qlocal, 256, 256, 3136);
    // 2. dwconv s2 + BN0
    dwconv_bn<<<dim3(12544), 256, 0, stream>>>(x, p0_w, p0_b, bn0_g, bn0_b, bn0_m, bn0_v,
                                               p0, 56, 56, 28, 28, 2, 3211264);
    // 3. pl0 (1x1)
    gemm1x1_mfma<<<dim3(7, 2, 16), 256, 0, stream>>>(p0, pl0_w, pl0_b, pl0, 256, 256, 784);
    // 4. dwconv s2 + BN1
    dwconv_bn<<<dim3(3136), 256, 0, stream>>>(pl0, p1_w, p1_b, bn1_g, bn1_b, bn1_m, bn1_v,
                                              p1, 28, 28, 14, 14, 2, 802816);
    // 5. kv projection (1x1, Co=512)
    gemm1x1_mfma<<<dim3(2, 4, 16), 256, 0, stream>>>(p1, kv_w, kv_b, kv, 256, 512, 196);
    // 6. attention -> global_feat
    attn_kernel<<<dim3(7, 8, 16), 512, 0, stream>>>(qlocal, kv, gf);
    // 7. local dwconv + silu + gating -> t
    gate_kernel<<<dim3(50176), 256, 0, stream>>>(qlocal, loc_w, loc_b, gf, tb, 12845056);
    // 8. mix (1x1) -> d_out
    gemm1x1_mfma<<<dim3(25, 2, 16), 256, 0, stream>>>(tb, mix_w, mix_b, qlocal, 256, 256, 3136);
}